// Round 7
// baseline (411.864 us; speedup 1.0000x reference)
//
#include <hip/hip_runtime.h>
#include <math.h>

typedef unsigned short ushort_t;
typedef unsigned int   uint32;
typedef __attribute__((ext_vector_type(8)))  short bf16x8;
typedef __attribute__((ext_vector_type(16))) float f32x16;

#define EMB     512
#define NROWS   8192
#define NITEMS  4096
#define NSPLIT  8
#define CPS     1024     // candidates per split
#define CTILE   256      // candidate tile (4 per split)
#define QTILE   128      // queries per block
#define KSLAB   32       // K per staged step
#define NSTEPS  64       // 4 ct * 16 kk
#define LDEPTH  12
#define KEEP    16

#define GLOAD_LDS(gp, lp) __builtin_amdgcn_global_load_lds( \
    (const __attribute__((address_space(1))) void*)(gp),    \
    (__attribute__((address_space(3))) void*)(lp), 16, 0, 0)

__device__ inline ushort_t f2bf(float x) {
    uint32 u = __float_as_uint(x);
    uint32 r = (u + 0x7FFFu + ((u >> 16) & 1u)) >> 16;
    return (ushort_t)r;
}

// monotone float->u32, truncate low 13 bits, embed (8191-idx): lowest idx wins ties
__device__ inline uint32 packkey(float v, int idx) {
    uint32 u = __float_as_uint(v);
    uint32 s = u ^ ((u & 0x80000000u) ? 0xFFFFFFFFu : 0x80000000u);
    return (s & 0xFFFFE000u) | ((uint32)idx ^ 0x1FFFu);
}

// ---------------- Phase A: fp64 norms + normalized-bf16 plane ----------------
__global__ void prep_kernel(const float* __restrict__ E,
                            ushort_t* __restrict__ Xbf, double* __restrict__ invd) {
    const int row  = blockIdx.x * 4 + (threadIdx.x >> 6);
    const int lane = threadIdx.x & 63;
    const float4* p = (const float4*)(E + (size_t)row * EMB);
    float4 f0 = p[lane];
    float4 f1 = p[lane + 64];
    double s = (double)f0.x*f0.x + (double)f0.y*f0.y + (double)f0.z*f0.z + (double)f0.w*f0.w
             + (double)f1.x*f1.x + (double)f1.y*f1.y + (double)f1.z*f1.z + (double)f1.w*f1.w;
#pragma unroll
    for (int m = 32; m > 0; m >>= 1) s += __shfl_xor(s, m);
    const double inv = 1.0 / sqrt(s);
    if (lane == 0) invd[row] = inv;
    const float invf = (float)inv;
    float x[8] = {f0.x, f0.y, f0.z, f0.w, f1.x, f1.y, f1.z, f1.w};
    ushort_t h[8];
#pragma unroll
    for (int q = 0; q < 8; ++q) h[q] = f2bf(x[q] * invf);
    ushort4* H = (ushort4*)(Xbf + (size_t)row * EMB);
    H[lane]      = make_ushort4(h[0], h[1], h[2], h[3]);
    H[lane + 64] = make_ushort4(h[4], h[5], h[6], h[7]);
}

// ---------------- Phase B: dbuf bf16 32x32x16 MFMA, 256x128 tile, top-12/lane ----------------
// (byte-identical to round 5/6 — passed, absmax 0)
__global__ __launch_bounds__(256, 2) void sim_topk_mfma(
    const ushort_t* __restrict__ Xbf, uint32* __restrict__ keys_out) {

    __shared__ union {
        struct { ushort_t A[2][8192]; ushort_t B[2][4096]; } s;  // 48 KB dbuf staging
        struct { uint32 mk[128][65]; } m;                         // 33.3 KB merge
    } sh;

    const int t     = threadIdx.x;
    const int lane  = t & 63;
    const int wave  = t >> 6;
    const int wm    = wave >> 1;
    const int wn    = wave & 1;
    const int rb    = blockIdx.x >> 3;
    const int split = blockIdx.x & 7;
    const int qbase = rb * QTILE;
    const int l31   = lane & 31;
    const int l5    = lane >> 5;

    int  laneoff[6];
    int  ldsoff[6];
    bool isA[6];
#pragma unroll
    for (int c = 0; c < 6; ++c) {
        const int G = wave * 6 + c;
        const bool a = (G < 16);
        const int idx = a ? G : (G - 16);
        const int row = (idx >> 1) * 32 + l31;
        const int oct = (idx & 1) * 2 + l5;
        laneoff[c] = row * EMB + oct * 8;
        ldsoff[c]  = idx * 512;
        isA[c]     = a;
    }
    const int qoff = qbase * EMB;

    auto stage = [&](int cand0, int kk, int buf) {
#pragma unroll
        for (int c = 0; c < 6; ++c) {
            const int goff = laneoff[c] + kk + (isA[c] ? cand0 * EMB : qoff);
            ushort_t* lp = isA[c] ? (sh.s.A[buf] + ldsoff[c]) : (sh.s.B[buf] + ldsoff[c]);
            GLOAD_LDS(Xbf + goff, lp);
        }
    };

    uint32 tv[2][LDEPTH];
#pragma unroll
    for (int fc = 0; fc < 2; ++fc)
#pragma unroll
        for (int s = 0; s < LDEPTH; ++s) tv[fc][s] = 0u;

    f32x16 acc[4][2];
#pragma unroll
    for (int fr = 0; fr < 4; ++fr)
#pragma unroll
        for (int fc = 0; fc < 2; ++fc)
#pragma unroll
            for (int q = 0; q < 16; ++q) acc[fr][fc][q] = 0.f;

    stage(split * CPS + 0 * CTILE, 0, 0);

#pragma unroll 1
    for (int s = 0; s < NSTEPS; ++s) {
        const int ct   = s >> 4;
        const int buf  = s & 1;
        const int cand0 = split * CPS + ct * CTILE;

        __syncthreads();

        if (s + 1 < NSTEPS) {
            const int s2 = s + 1;
            stage(split * CPS + (s2 >> 4) * CTILE, (s2 & 15) * KSLAB, s2 & 1);
        }

        bf16x8 aH[4][2], bH[2][2];
#pragma unroll
        for (int fr = 0; fr < 4; ++fr)
#pragma unroll
            for (int kt = 0; kt < 2; ++kt)
                aH[fr][kt] = *(const bf16x8*)&sh.s.A[buf][((wm * 4 + fr) * 128 + kt * 64 + lane) * 8];
#pragma unroll
        for (int fc = 0; fc < 2; ++fc)
#pragma unroll
            for (int kt = 0; kt < 2; ++kt)
                bH[fc][kt] = *(const bf16x8*)&sh.s.B[buf][((wn * 2 + fc) * 128 + kt * 64 + lane) * 8];

#pragma unroll
        for (int kt = 0; kt < 2; ++kt)
#pragma unroll
            for (int fr = 0; fr < 4; ++fr)
#pragma unroll
                for (int fc = 0; fc < 2; ++fc)
                    acc[fr][fc] = __builtin_amdgcn_mfma_f32_32x32x16_bf16(
                        aH[fr][kt], bH[fc][kt], acc[fr][fc], 0, 0, 0);

        if ((s & 15) == 15) {
#pragma unroll
            for (int fc = 0; fc < 2; ++fc) {
#pragma unroll
                for (int fr = 0; fr < 4; ++fr) {
                    float m0 = fmaxf(fmaxf(acc[fr][fc][0],  acc[fr][fc][1]),  fmaxf(acc[fr][fc][2],  acc[fr][fc][3]));
                    float m1 = fmaxf(fmaxf(acc[fr][fc][4],  acc[fr][fc][5]),  fmaxf(acc[fr][fc][6],  acc[fr][fc][7]));
                    float m2 = fmaxf(fmaxf(acc[fr][fc][8],  acc[fr][fc][9]),  fmaxf(acc[fr][fc][10], acc[fr][fc][11]));
                    float m3 = fmaxf(fmaxf(acc[fr][fc][12], acc[fr][fc][13]), fmaxf(acc[fr][fc][14], acc[fr][fc][15]));
                    float mx = fmaxf(fmaxf(m0, m1), fmaxf(m2, m3));
                    if (packkey(mx, 0) > tv[fc][LDEPTH - 1]) {
                        const int jb = cand0 + wm * 128 + fr * 32 + (l5 << 2);
#pragma unroll
                        for (int reg = 0; reg < 16; ++reg) {
                            const int ci = jb + (reg & 3) + ((reg >> 2) << 3);
                            uint32 key = packkey(acc[fr][fc][reg], ci);
                            if (key > tv[fc][LDEPTH - 1]) {
                                uint32 cur = key;
#pragma unroll
                                for (int d = 0; d < LDEPTH; ++d) {
                                    uint32 a  = tv[fc][d];
                                    bool   gt = cur > a;
                                    tv[fc][d] = gt ? cur : a;
                                    cur       = gt ? a : cur;
                                }
                            }
                        }
                    }
#pragma unroll
                    for (int q = 0; q < 16; ++q) acc[fr][fc][q] = 0.f;
                }
            }
        }
    }

    __syncthreads();
#pragma unroll
    for (int fc = 0; fc < 2; ++fc) {
        const int col = wn * 64 + fc * 32 + l31;
        const int sl  = wm * 2 + l5;
#pragma unroll
        for (int d = 0; d < LDEPTH; ++d) sh.m.mk[col][sl * 16 + d] = tv[fc][d];
#pragma unroll
        for (int d = LDEPTH; d < 16; ++d) sh.m.mk[col][sl * 16 + d] = 0u;
    }
    __syncthreads();
    if (t < 128) {
        int p[4] = {0, 0, 0, 0};
        const size_t base = ((size_t)(qbase + t) * NSPLIT + split) * KEEP;
#pragma unroll 1
        for (int sel = 0; sel < KEEP; ++sel) {
            uint32 bk = 0; int bl = 0;
#pragma unroll
            for (int l = 0; l < 4; ++l) {
                uint32 k = sh.m.mk[t][l * 16 + p[l]];
                if (k > bk) { bk = k; bl = l; }
            }
            p[bl]++;
            keys_out[base + sel] = bk;
        }
    }
}

// ---------------- Phase C: one row per block — parallel rank + fp64 rescue ----------------
__global__ __launch_bounds__(256) void rescue_kernel(
    const float* __restrict__ E, const double* __restrict__ invd,
    const uint32* __restrict__ keys,
    const int* __restrict__ n_users, const int* __restrict__ n_entitys,
    const int* __restrict__ interactions, float* __restrict__ out) {

    __shared__ uint32 skeys[128];
    __shared__ float4 sq[128];        // this row's Q (512 floats)
    __shared__ int    scand[16];
    __shared__ double sd[16];
    __shared__ int    sci[16];
    __shared__ float  smemb[16];
    __shared__ double contrib[8];

    const int t   = threadIdx.x;
    const int row = blockIdx.x;

    if (t < 128) {
        skeys[t] = keys[(size_t)row * 128 + t];
        sq[t]    = ((const float4*)(E + (size_t)row * EMB))[t];
    }
    if (t < 16) scand[t] = 0;          // poison-proof: no slot ever garbage
    if (t < 8)  contrib[t] = 0.0;
    __syncthreads();

    // parallel rank-select over 128 keys (unique ranks via slot tie-break)
    if (t < 128) {
        const uint32 k = skeys[t];
        int r = 0;
#pragma unroll 16
        for (int j = 0; j < 128; ++j) {
            const uint32 kj = skeys[j];       // broadcast LDS read
            r += (kj > k) || (kj == k && j < t);
        }
        if (r < 16) scand[r] = (int)((k & 0x1FFFu) ^ 0x1FFFu);
    }
    __syncthreads();

    // 16 groups x 16 lanes: exact fp64 dot per candidate
    const int g    = t >> 4;
    const int l16  = t & 15;
    const int cand = scand[g] & (NROWS - 1);   // always in-bounds
    const float4* C = (const float4*)(E + (size_t)cand * EMB);
    double acc = 0.0;
#pragma unroll
    for (int j = 0; j < 8; ++j) {
        float4 c = C[l16 + 16 * j];            // 16 lanes = 256B contiguous
        float4 q = sq[l16 + 16 * j];           // broadcast across groups
        acc += (double)q.x * c.x + (double)q.y * c.y
             + (double)q.z * c.z + (double)q.w * c.w;
    }
#pragma unroll
    for (int m = 8; m >= 1; m >>= 1) acc += __shfl_xor(acc, m, 16);

    const int ent = n_entitys[row];
    if (l16 == 0) { sd[g] = acc * invd[row] * invd[cand]; sci[g] = cand; }
    if (l16 == 1) {                            // 16 gathers in flight per block
        const int uid = n_users[cand];
        smemb[g] = (float)interactions[(size_t)uid * NITEMS + ent];
    }
    __syncthreads();

    // parallel exact top-6: rank 16 sims (value desc, idx asc, slot tie-break)
    if (t < 16) {
        const double v  = sd[t];
        const int    ci = sci[t];
        int r = 0;
#pragma unroll
        for (int j = 0; j < 16; ++j) {
            const double vj = sd[j];
            const int    cj = sci[j];
            r += (vj > v) || (vj == v && (cj < ci || (cj == ci && j < t)));
        }
        if (r < 6) contrib[r] = v * (double)smemb[t];
    }
    __syncthreads();
    if (t == 0) {
        const double sum = contrib[0] + contrib[1] + contrib[2]
                         + contrib[3] + contrib[4] + contrib[5];
        out[row] = (float)(sum * (1.0 / 6.0));
    }
}

extern "C" void kernel_launch(void* const* d_in, const int* in_sizes, int n_in,
                              void* d_out, int out_size, void* d_ws, size_t ws_size,
                              hipStream_t stream) {
    const float* E            = (const float*)d_in[0];
    const int*   n_users      = (const int*)d_in[1];
    const int*   n_entitys    = (const int*)d_in[2];
    const int*   interactions = (const int*)d_in[3];
    float*       out          = (float*)d_out;

    ushort_t* Xbf  = (ushort_t*)d_ws;
    double*   invd = (double*)(Xbf + (size_t)NROWS * EMB);
    uint32*   keys = (uint32*)(invd + NROWS);

    prep_kernel<<<NROWS / 4, 256, 0, stream>>>(E, Xbf, invd);
    sim_topk_mfma<<<(NROWS / QTILE) * NSPLIT, 256, 0, stream>>>(Xbf, keys);
    rescue_kernel<<<NROWS, 256, 0, stream>>>(E, invd, keys, n_users, n_entitys,
                                             interactions, out);
}

// Round 8
// 377.392 us; speedup vs baseline: 1.0913x; 1.0913x over previous
//
#include <hip/hip_runtime.h>
#include <math.h>

typedef unsigned char  uchar_t;
typedef unsigned int   uint32;
typedef __attribute__((ext_vector_type(4)))  int   i32x4;
typedef __attribute__((ext_vector_type(8)))  int   i32x8;
typedef __attribute__((ext_vector_type(16))) float f32x16;

#define EMB     512
#define NROWS   8192
#define NITEMS  4096
#define NSPLIT  8
#define CPS     1024     // candidates per split
#define CTILE   256      // candidate tile rows (4 per split)
#define QTILE   128      // queries per block
#define NSTEPS  32       // 4 ct * 8 kslabs of K=64
#define LDEPTH  12
#define KEEP    16
#define NRESC   32       // candidates re-scored exactly per row

#define GLOAD_LDS(gp, lp) __builtin_amdgcn_global_load_lds( \
    (const __attribute__((address_space(1))) void*)(gp),    \
    (__attribute__((address_space(3))) void*)(lp), 16, 0, 0)

// monotone float->u32, truncate low 13 bits, embed (8191-idx): lowest idx wins ties
__device__ inline uint32 packkey(float v, int idx) {
    uint32 u = __float_as_uint(v);
    uint32 s = u ^ ((u & 0x80000000u) ? 0xFFFFFFFFu : 0x80000000u);
    return (s & 0xFFFFE000u) | ((uint32)idx ^ 0x1FFFu);
}

// ---------------- Phase A: fp64 norms + normalized fp8(e4m3, x16) plane ----------------
__global__ void prep_kernel(const float* __restrict__ E,
                            uchar_t* __restrict__ Xq, double* __restrict__ invd) {
    const int row  = blockIdx.x * 4 + (threadIdx.x >> 6);
    const int lane = threadIdx.x & 63;
    const float4* p = (const float4*)(E + (size_t)row * EMB);
    float4 f0 = p[lane];
    float4 f1 = p[lane + 64];
    double s = (double)f0.x*f0.x + (double)f0.y*f0.y + (double)f0.z*f0.z + (double)f0.w*f0.w
             + (double)f1.x*f1.x + (double)f1.y*f1.y + (double)f1.z*f1.z + (double)f1.w*f1.w;
#pragma unroll
    for (int m = 32; m > 0; m >>= 1) s += __shfl_xor(s, m);
    const double inv = 1.0 / sqrt(s);
    if (lane == 0) invd[row] = inv;
    const float sc = (float)inv * 16.0f;    // x16: centers e4m3 range; sims scale x256 (monotone)
    int w0 = 0, w1 = 0;
    w0 = __builtin_amdgcn_cvt_pk_fp8_f32(f0.x * sc, f0.y * sc, w0, false);
    w0 = __builtin_amdgcn_cvt_pk_fp8_f32(f0.z * sc, f0.w * sc, w0, true);
    w1 = __builtin_amdgcn_cvt_pk_fp8_f32(f1.x * sc, f1.y * sc, w1, false);
    w1 = __builtin_amdgcn_cvt_pk_fp8_f32(f1.z * sc, f1.w * sc, w1, true);
    ((int2*)(Xq + (size_t)row * EMB))[lane] = make_int2(w0, w1);
}

// ---------------- Phase B: dbuf MX-fp8 32x32x64 MFMA, 256x128 tile, top-12/lane ----------------
// LDS tile layout: 32-row chunk c, 16B-granule op (0..3 across 64B K-slab):
//   byte addr = c*2048 + op*512 + (row&31)*16
// DMA j (1KB): chunk j>>1, ops {2(j&1), 2(j&1)+1}; lane l -> slot l*16 exactly.
// Frag read (chunk ca): two b128 at ca*2048 + i*512 + (l>>5)*1024 + (l&31)*16, i=0,1
//   => lane l holds row l&31, K-bytes (l>>5)*32 + [0..32)  (A-operand layout for 32x32x64)
__global__ __launch_bounds__(256, 2) void sim_topk_mfma(
    const uchar_t* __restrict__ Xq, uint32* __restrict__ keys_out) {

    __shared__ union {
        struct { uchar_t A[2][16384]; uchar_t B[2][8192]; } s;  // 48 KB dbuf staging
        struct { uint32 mk[128][65]; } m;                        // 33.3 KB merge
    } sh;

    const int t     = threadIdx.x;
    const int lane  = t & 63;
    const int wave  = t >> 6;
    const int wm    = wave >> 1;          // candidate half: rows wm*128..+128
    const int wn    = wave & 1;           // query half: cols wn*64..+64
    const int rb    = blockIdx.x >> 3;
    const int split = blockIdx.x & 7;
    const int qbase = rb * QTILE;
    const int l31   = lane & 31;
    const int l5    = lane >> 5;

    // 24 DMAs/step (A:16, B:8) -> 6 per wave
    int  laneglob[6];   // byte offset within (tile, kslab)
    int  ldsoff[6];     // byte offset within A- or B-region (wave-uniform)
    bool isAf[6];
#pragma unroll
    for (int c = 0; c < 6; ++c) {
        const int G = wave * 6 + c;
        const bool a = (G < 16);
        const int j = a ? G : (G - 16);
        const int rowin = (j >> 1) * 32 + l31;
        const int kb    = (((j & 1) << 1) + l5) << 4;
        laneglob[c] = rowin * EMB + kb;
        ldsoff[c]   = j * 1024;
        isAf[c]     = a;
    }

    auto stage = [&](int cand0, int kslab, int buf) {
#pragma unroll
        for (int c = 0; c < 6; ++c) {
            const size_t goff = (size_t)(isAf[c] ? cand0 : qbase) * EMB + kslab + laneglob[c];
            uchar_t* lp = (isAf[c] ? sh.s.A[buf] : sh.s.B[buf]) + ldsoff[c];
            GLOAD_LDS(Xq + goff, lp);
        }
    };

    uint32 tv[2][LDEPTH];
#pragma unroll
    for (int fc = 0; fc < 2; ++fc)
#pragma unroll
        for (int s = 0; s < LDEPTH; ++s) tv[fc][s] = 0u;

    f32x16 acc[4][2];
#pragma unroll
    for (int fr = 0; fr < 4; ++fr)
#pragma unroll
        for (int fc = 0; fc < 2; ++fc)
#pragma unroll
            for (int q = 0; q < 16; ++q) acc[fr][fc][q] = 0.f;

    stage(split * CPS, 0, 0);   // prologue

    const int fo = (l5 << 10) + (l31 << 4);   // frag lane offset

#pragma unroll 1
    for (int s = 0; s < NSTEPS; ++s) {
        const int buf   = s & 1;
        const int cand0 = split * CPS + (s >> 3) * CTILE;

        __syncthreads();   // drains this step's DMA (issued one compute-phase ago)

        if (s + 1 < NSTEPS) {
            const int s2 = s + 1;
            stage(split * CPS + (s2 >> 3) * CTILE, (s2 & 7) * 64, s2 & 1);
        }

        i32x8 af[4], bf[2];
#pragma unroll
        for (int fr = 0; fr < 4; ++fr) {
            const int ca = (wm * 4 + fr) * 2048;
            i32x4 lo = *(const i32x4*)&sh.s.A[buf][ca + fo];
            i32x4 hi = *(const i32x4*)&sh.s.A[buf][ca + 512 + fo];
            i32x8 v;
            v[0] = lo[0]; v[1] = lo[1]; v[2] = lo[2]; v[3] = lo[3];
            v[4] = hi[0]; v[5] = hi[1]; v[6] = hi[2]; v[7] = hi[3];
            af[fr] = v;
        }
#pragma unroll
        for (int fc = 0; fc < 2; ++fc) {
            const int cb = (wn * 2 + fc) * 2048;
            i32x4 lo = *(const i32x4*)&sh.s.B[buf][cb + fo];
            i32x4 hi = *(const i32x4*)&sh.s.B[buf][cb + 512 + fo];
            i32x8 v;
            v[0] = lo[0]; v[1] = lo[1]; v[2] = lo[2]; v[3] = lo[3];
            v[4] = hi[0]; v[5] = hi[1]; v[6] = hi[2]; v[7] = hi[3];
            bf[fc] = v;
        }

#pragma unroll
        for (int fr = 0; fr < 4; ++fr)
#pragma unroll
            for (int fc = 0; fc < 2; ++fc)
                acc[fr][fc] = __builtin_amdgcn_mfma_scale_f32_32x32x64_f8f6f4(
                    af[fr], bf[fc], acc[fr][fc],
                    0, 0,                 // cbsz=fp8(e4m3), blgp=fp8(e4m3)
                    0, 0x7F7F7F7F,        // scale A = 1.0 (all E8M0 bytes 127)
                    0, 0x7F7F7F7F);       // scale B = 1.0

        if ((s & 7) == 7) {
            // ---- register-only epilogue: packed-key insert into per-lane top-12 ----
#pragma unroll
            for (int fc = 0; fc < 2; ++fc) {
#pragma unroll
                for (int fr = 0; fr < 4; ++fr) {
                    float m0 = fmaxf(fmaxf(acc[fr][fc][0],  acc[fr][fc][1]),  fmaxf(acc[fr][fc][2],  acc[fr][fc][3]));
                    float m1 = fmaxf(fmaxf(acc[fr][fc][4],  acc[fr][fc][5]),  fmaxf(acc[fr][fc][6],  acc[fr][fc][7]));
                    float m2 = fmaxf(fmaxf(acc[fr][fc][8],  acc[fr][fc][9]),  fmaxf(acc[fr][fc][10], acc[fr][fc][11]));
                    float m3 = fmaxf(fmaxf(acc[fr][fc][12], acc[fr][fc][13]), fmaxf(acc[fr][fc][14], acc[fr][fc][15]));
                    float mx = fmaxf(fmaxf(m0, m1), fmaxf(m2, m3));
                    if (packkey(mx, 0) > tv[fc][LDEPTH - 1]) {
                        const int jb = cand0 + wm * 128 + fr * 32 + (l5 << 2);
#pragma unroll
                        for (int reg = 0; reg < 16; ++reg) {
                            const int ci = jb + (reg & 3) + ((reg >> 2) << 3);
                            uint32 key = packkey(acc[fr][fc][reg], ci);
                            if (key > tv[fc][LDEPTH - 1]) {
                                uint32 cur = key;
#pragma unroll
                                for (int d = 0; d < LDEPTH; ++d) {
                                    uint32 a  = tv[fc][d];
                                    bool   gt = cur > a;
                                    tv[fc][d] = gt ? cur : a;
                                    cur       = gt ? a : cur;
                                }
                            }
                        }
                    }
#pragma unroll
                    for (int q = 0; q < 16; ++q) acc[fr][fc][q] = 0.f;
                }
            }
        }
    }

    // ---- merge 4 lane-lists per query, emit sorted top-16 keys ----
    __syncthreads();
#pragma unroll
    for (int fc = 0; fc < 2; ++fc) {
        const int col = wn * 64 + fc * 32 + l31;
        const int sl  = wm * 2 + l5;
#pragma unroll
        for (int d = 0; d < LDEPTH; ++d) sh.m.mk[col][sl * 16 + d] = tv[fc][d];
#pragma unroll
        for (int d = LDEPTH; d < 16; ++d) sh.m.mk[col][sl * 16 + d] = 0u;
    }
    __syncthreads();
    if (t < 128) {
        int p[4] = {0, 0, 0, 0};
        const size_t base = ((size_t)(qbase + t) * NSPLIT + split) * KEEP;
#pragma unroll 1
        for (int sel = 0; sel < KEEP; ++sel) {
            uint32 bk = 0; int bl = 0;
#pragma unroll
            for (int l = 0; l < 4; ++l) {
                uint32 k = sh.m.mk[t][l * 16 + p[l]];
                if (k > bk) { bk = k; bl = l; }
            }
            p[bl]++;
            keys_out[base + sel] = bk;
        }
    }
}

// ---------------- Phase C: one row per block — rank-select top-32 + fp64 rescue ----------------
__global__ __launch_bounds__(256) void rescue_kernel(
    const float* __restrict__ E, const double* __restrict__ invd,
    const uint32* __restrict__ keys,
    const int* __restrict__ n_users, const int* __restrict__ n_entitys,
    const int* __restrict__ interactions, float* __restrict__ out) {

    __shared__ uint32 skeys[128];
    __shared__ float4 sq[128];        // this row's Q (512 floats)
    __shared__ int    scand[NRESC];
    __shared__ double sd[NRESC];
    __shared__ int    sci[NRESC];
    __shared__ float  smemb[NRESC];
    __shared__ double contrib[8];

    const int t   = threadIdx.x;
    const int row = blockIdx.x;

    if (t < 128) {
        skeys[t] = keys[(size_t)row * 128 + t];
        sq[t]    = ((const float4*)(E + (size_t)row * EMB))[t];
    }
    if (t < NRESC) scand[t] = 0;      // poison-proof: no slot ever garbage
    if (t < 8)     contrib[t] = 0.0;
    __syncthreads();

    // parallel rank-select over 128 keys (unique ranks via slot tie-break)
    if (t < 128) {
        const uint32 k = skeys[t];
        int r = 0;
#pragma unroll 16
        for (int j = 0; j < 128; ++j) {
            const uint32 kj = skeys[j];       // broadcast LDS read
            r += (kj > k) || (kj == k && j < t);
        }
        if (r < NRESC) scand[r] = (int)((k & 0x1FFFu) ^ 0x1FFFu);
    }
    __syncthreads();

    // 32 groups x 8 lanes: exact fp64 dot per candidate
    const int g    = t >> 3;
    const int l8   = t & 7;
    const int cand = scand[g] & (NROWS - 1);   // always in-bounds
    const float4* C = (const float4*)(E + (size_t)cand * EMB);
    double acc = 0.0;
#pragma unroll
    for (int j = 0; j < 16; ++j) {
        float4 c = C[l8 + 8 * j];              // 8 lanes = 128B contiguous
        float4 q = sq[l8 + 8 * j];             // broadcast across groups
        acc += (double)q.x * c.x + (double)q.y * c.y
             + (double)q.z * c.z + (double)q.w * c.w;
    }
#pragma unroll
    for (int m = 4; m >= 1; m >>= 1) acc += __shfl_xor(acc, m, 8);

    const int ent = n_entitys[row];
    if (l8 == 0) { sd[g] = acc * invd[row] * invd[cand]; sci[g] = cand; }
    if (l8 == 1) {                             // 32 gathers in flight per block
        const int uid = n_users[cand];
        smemb[g] = (float)interactions[(size_t)uid * NITEMS + ent];
    }
    __syncthreads();

    // parallel exact top-6: rank 32 sims (value desc, idx asc, slot tie-break)
    if (t < NRESC) {
        const double v  = sd[t];
        const int    ci = sci[t];
        int r = 0;
#pragma unroll
        for (int j = 0; j < NRESC; ++j) {
            const double vj = sd[j];
            const int    cj = sci[j];
            r += (vj > v) || (vj == v && (cj < ci || (cj == ci && j < t)));
        }
        if (r < 6) contrib[r] = v * (double)smemb[t];
    }
    __syncthreads();
    if (t == 0) {
        const double sum = contrib[0] + contrib[1] + contrib[2]
                         + contrib[3] + contrib[4] + contrib[5];
        out[row] = (float)(sum * (1.0 / 6.0));
    }
}

extern "C" void kernel_launch(void* const* d_in, const int* in_sizes, int n_in,
                              void* d_out, int out_size, void* d_ws, size_t ws_size,
                              hipStream_t stream) {
    const float* E            = (const float*)d_in[0];
    const int*   n_users      = (const int*)d_in[1];
    const int*   n_entitys    = (const int*)d_in[2];
    const int*   interactions = (const int*)d_in[3];
    float*       out          = (float*)d_out;

    // ws: Xq fp8 [4 MB] | invd [64 KB] | keys [4 MB]
    uchar_t* Xq   = (uchar_t*)d_ws;
    double*  invd = (double*)(Xq + (size_t)NROWS * EMB);
    uint32*  keys = (uint32*)(invd + NROWS);

    prep_kernel<<<NROWS / 4, 256, 0, stream>>>(E, Xq, invd);
    sim_topk_mfma<<<(NROWS / QTILE) * NSPLIT, 256, 0, stream>>>(Xq, keys);
    rescue_kernel<<<NROWS, 256, 0, stream>>>(E, invd, keys, n_users, n_entitys,
                                             interactions, out);
}